// Round 5
// baseline (2005.678 us; speedup 1.0000x reference)
//
#include <hip/hip_runtime.h>
#include <stdint.h>

// ---------------- problem constants ----------------
#define TT 512
#define BB 256
#define HH 256
#define II 128
#define OUTD 128
#define EPSV 1e-5f

// ---------------- geometry ----------------
// 32 clusters x 8 batch rows; 4 WGs (stages) of 512 thr per cluster, one WG/CU.
//   M1: gi1 = x@Wih1^T   A: h1 recurrence   M2: gi2 = h1@Wih2^T   B: h2 + BN
// v6 sync schedule (v4 measured 3.46us/step, ~90% stall on ring RTs):
//  - posts every 2 steps, at iteration END, after a counted vmcnt that leaves
//    the current iteration's ops outstanding (post-drain off the common path)
//  - polls every 8 steps (fwd +10/+11, back -24; windows 7-8 iters of slack;
//    slot-alias safety verified against RD=32 with poll granularity +7)
//  - prefetch-2 on all ring reads (double-buffered reg sets, unroll-2 for
//    static indexing)
// Post semantics: P=k => ring stores of steps <= k are vmcnt-complete (forced
// by the pre-post counted vmcnt one+ iterations later than issue).
#define NCL 32
#define RPC 8
#define RD1 32
#define RD2 32
#define HPAD 264
#define SPIN_CAP (1 << 17)

#define P_M1 0
#define P_A  1
#define P_M2 2
#define P_B  3

// ---------------- workspace layout (bytes), total ~100 MB ----------------
#define OFF_PROG     0u
#define OFF_BNSUM    1024u
#define OFF_BNSQ     2048u
#define OFF_ZERO_END 3072u
#define OFF_GI1      65536u
#define GI_SLOT      16384u                        // rz bf16 8KB + n fp32 8KB
#define GI1_BYTES    ((unsigned)NCL*RD1*GI_SLOT)   // 16 MB
#define OFF_H1R      (OFF_GI1 + GI1_BYTES)
#define H1R_BYTES    ((unsigned)NCL*RD2*4096u)     // 4 MB
#define OFF_GI2      (OFF_H1R + H1R_BYTES)
#define GI2_BYTES    ((unsigned)NCL*RD2*GI_SLOT)   // 16 MB
#define OFF_H2SEQ    (OFF_GI2 + GI2_BYTES)         // 64 MB bf16 [t][b][h]

typedef short bf16x8 __attribute__((ext_vector_type(8)));
typedef float f32x4  __attribute__((ext_vector_type(4)));
typedef unsigned long long u64;

__device__ __forceinline__ short f2bf(float v) {
    unsigned u = __float_as_uint(v);
    u += 0x7fffu + ((u >> 16) & 1u);
    return (short)(u >> 16);
}
__device__ __forceinline__ float bf2f(short s) {
    return __uint_as_float(((unsigned)(unsigned short)s) << 16);
}
__device__ __forceinline__ float bf2f_lo(unsigned u) { return __uint_as_float(u << 16); }
__device__ __forceinline__ float bf2f_hi(unsigned u) { return __uint_as_float(u & 0xffff0000u); }
__device__ __forceinline__ unsigned pk2bf(float a, float b) {
    return (unsigned)(unsigned short)f2bf(a) | ((unsigned)(unsigned short)f2bf(b) << 16);
}
__device__ __forceinline__ bf16x8 ldfrag_f32(const float* __restrict__ p) {
    const float4* q = (const float4*)p;
    float4 a = q[0], b = q[1];
    bf16x8 f;
    f[0]=f2bf(a.x); f[1]=f2bf(a.y); f[2]=f2bf(a.z); f[3]=f2bf(a.w);
    f[4]=f2bf(b.x); f[5]=f2bf(b.y); f[6]=f2bf(b.z); f[7]=f2bf(b.w);
    return f;
}
__device__ __forceinline__ float sigm_f(float x) {
    float e = __expf(-x);
    return __builtin_amdgcn_rcpf(1.f + e);
}
__device__ __forceinline__ float tanh_f(float x) {
    float ax = fabsf(x);
    float e  = __expf(-2.f * ax);
    float t  = (1.f - e) * __builtin_amdgcn_rcpf(1.f + e);
    return copysignf(t, x);
}
__device__ __forceinline__ void poll_ge(const unsigned* p, int tgt) {
    if (tgt <= 0) return;
    int spins = 0;
    while ((int)__hip_atomic_load((unsigned*)p, __ATOMIC_RELAXED, __HIP_MEMORY_SCOPE_SYSTEM) < tgt) {
        __builtin_amdgcn_s_sleep(2);
        if (++spins > SPIN_CAP) break;       // watchdog
    }
    asm volatile("" ::: "memory");
}
__device__ __forceinline__ void poll2_ge(const unsigned* p1, int t1, const unsigned* p2, int t2) {
    int spins = 0;
    for (;;) {
        int a = (int)__hip_atomic_load((unsigned*)p1, __ATOMIC_RELAXED, __HIP_MEMORY_SCOPE_SYSTEM);
        int b = (int)__hip_atomic_load((unsigned*)p2, __ATOMIC_RELAXED, __HIP_MEMORY_SCOPE_SYSTEM);
        if (a >= t1 && b >= t2) break;
        __builtin_amdgcn_s_sleep(2);
        if (++spins > SPIN_CAP) break;       // watchdog
    }
    asm volatile("" ::: "memory");
}
__device__ __forceinline__ void post_prog(unsigned* p, int v) {
    __hip_atomic_store(p, (unsigned)v, __ATOMIC_RELAXED, __HIP_MEMORY_SCOPE_SYSTEM);
}
__device__ __forceinline__ unsigned ld_u32_coh(const unsigned* p) {
    return __hip_atomic_load((unsigned*)p, __ATOMIC_RELAXED, __HIP_MEMORY_SCOPE_SYSTEM);
}
__device__ __forceinline__ void st_u32_coh(unsigned* p, unsigned v) {
    __hip_atomic_store(p, v, __ATOMIC_RELAXED, __HIP_MEMORY_SCOPE_SYSTEM);
}
__device__ __forceinline__ u64 ld_u64_coh(const u64* p) {
    return __hip_atomic_load((u64*)p, __ATOMIC_RELAXED, __HIP_MEMORY_SCOPE_SYSTEM);
}
__device__ __forceinline__ void st_u64_coh(u64* p, u64 v) {
    __hip_atomic_store(p, v, __ATOMIC_RELAXED, __HIP_MEMORY_SCOPE_SYSTEM);
}
#define CFENCE() asm volatile("" ::: "memory")

// =============== persistent 4-stage pipeline ===============
__global__ void __launch_bounds__(512, 1)
gru_pipe(const float* __restrict__ x,
         const float* __restrict__ wih1, const float* __restrict__ whh1,
         const float* __restrict__ bih1, const float* __restrict__ bhh1,
         const float* __restrict__ wih2, const float* __restrict__ whh2,
         const float* __restrict__ bih2, const float* __restrict__ bhh2,
         char* __restrict__ ws)
{
    const int tid = threadIdx.x, wave = tid >> 6, lane = tid & 63;
    const int qd = lane >> 4, ln = lane & 15;
    const int stage = blockIdx.x & 3;
    const int cl    = blockIdx.x >> 2;
    const int grow0 = cl * RPC;

    unsigned* prog = (unsigned*)(ws + OFF_PROG) + cl * 4;
    short* h2seq = (short*)(ws + OFF_H2SEQ);

    __shared__ __align__(16) short hb[2][16][HPAD];
    {   // zero both buffers; garbage row-slots must stay 0 forever
        short* z = &hb[0][0][0];
        for (int i = tid; i < 2*16*HPAD; i += 512) z[i] = 0;
    }
    __syncthreads();

    if (stage == 0) {
        // ================= M1: gi1 producer (free-running) =================
        bf16x8 Wi[2][3][4]; f32x4 cinit[2][3];
        #pragma unroll
        for (int b2 = 0; b2 < 2; ++b2)
        #pragma unroll
        for (int g = 0; g < 3; ++g) {
            const int grow = g*256 + (wave*2 + b2)*16 + ln;
            #pragma unroll
            for (int kc = 0; kc < 4; ++kc)
                Wi[b2][g][kc] = ldfrag_f32(wih1 + grow*II + kc*32 + qd*8);
            float c0 = bih1[grow] + (g < 2 ? bhh1[grow] : 0.f);
            cinit[b2][g] = f32x4{c0, c0, c0, c0};
        }
        const float* xr = x + (size_t)(grow0 + (ln>>2)*2 + (ln&1)) * (TT*II) + qd*8;
        float4 xp[8];
        #pragma unroll
        for (int kc = 0; kc < 4; ++kc) {
            xp[2*kc]   = *(const float4*)(xr + kc*32);
            xp[2*kc+1] = *(const float4*)(xr + kc*32 + 4);
        }

        for (int t = 0; t < TT; ++t) {
            if ((t & 7) == 0) poll_ge(&prog[P_A], t - 24);    // gi1 ring backpressure
            CFENCE();
            bf16x8 a[4];
            #pragma unroll
            for (int kc = 0; kc < 4; ++kc) {
                float4 u = xp[2*kc], v = xp[2*kc+1];
                bf16x8 f;
                f[0]=f2bf(u.x); f[1]=f2bf(u.y); f[2]=f2bf(u.z); f[3]=f2bf(u.w);
                f[4]=f2bf(v.x); f[5]=f2bf(v.y); f[6]=f2bf(v.z); f[7]=f2bf(v.w);
                a[kc] = f;
            }
            if (t + 1 < TT) {
                const float* xn = xr + (size_t)(t+1)*II;
                #pragma unroll
                for (int kc = 0; kc < 4; ++kc) {
                    xp[2*kc]   = *(const float4*)(xn + kc*32);
                    xp[2*kc+1] = *(const float4*)(xn + kc*32 + 4);
                }
            }
            CFENCE();
            f32x4 acc[2][3];
            #pragma unroll
            for (int b2 = 0; b2 < 2; ++b2)
            #pragma unroll
            for (int g = 0; g < 3; ++g) acc[b2][g] = cinit[b2][g];
            #pragma unroll
            for (int kc = 0; kc < 4; ++kc)
            #pragma unroll
            for (int b2 = 0; b2 < 2; ++b2)
            #pragma unroll
            for (int g = 0; g < 3; ++g)
                acc[b2][g] = __builtin_amdgcn_mfma_f32_16x16x32_bf16(a[kc], Wi[b2][g][kc], acc[b2][g], 0, 0, 0);
            CFENCE();
            char* slot = ws + OFF_GI1 + ((size_t)cl*RD1 + (t & (RD1-1)))*GI_SLOT;
            unsigned* rz = (unsigned*)slot;
            u64* nn = (u64*)(slot + 8192);
            #pragma unroll
            for (int b2 = 0; b2 < 2; ++b2) {
                const int tile = wave*2 + b2;
                st_u32_coh(rz + (tile*2 + 0)*64 + lane, pk2bf(acc[b2][0][0], acc[b2][0][1]));
                st_u32_coh(rz + (tile*2 + 1)*64 + lane, pk2bf(acc[b2][1][0], acc[b2][1][1]));
                union { float f[2]; u64 u; } np;
                np.f[0] = acc[b2][2][0]; np.f[1] = acc[b2][2][1];
                st_u64_coh(nn + tile*64 + lane, np.u);
            }
            if (t & 1) {   // post t-1 after proving stores <= t-1 complete
                asm volatile("s_waitcnt vmcnt(14)" ::: "memory");
                if (tid == 0) post_prog(&prog[P_M1], t - 1);
            }
            asm volatile("s_waitcnt lgkmcnt(0)" ::: "memory");
            __builtin_amdgcn_sched_barrier(0);
            __builtin_amdgcn_s_barrier();
        }
        asm volatile("s_waitcnt vmcnt(0)" ::: "memory");
        __syncthreads();
        if (tid == 0) post_prog(&prog[P_M1], 1000000);

    } else if (stage == 1) {
        // ================= A: layer-1 recurrence =================
        bf16x8 Wh[2][3][8]; float bnn[2];
        #pragma unroll
        for (int b2 = 0; b2 < 2; ++b2) {
            const int colg = (wave*2 + b2)*16 + ln;
            #pragma unroll
            for (int g = 0; g < 3; ++g)
                #pragma unroll
                for (int kc = 0; kc < 8; ++kc)
                    Wh[b2][g][kc] = ldfrag_f32(whh1 + (g*256 + colg)*HH + kc*32 + qd*8);
            bnn[b2] = bhh1[512 + colg];
        }
        float hold[2][2] = {{0.f,0.f},{0.f,0.f}};
        unsigned pr0[2], pz0[2], pr1[2], pz1[2]; u64 pn0[2], pn1[2];
        const int tile0 = wave*2, tile1 = wave*2 + 1;

        // prologue: prefetch gi1(0) -> set0, gi1(1) -> set1
        poll_ge(&prog[P_M1], 2);
        #pragma unroll
        for (int s = 0; s < 2; ++s) {
            char* slot = ws + OFF_GI1 + ((size_t)cl*RD1 + s)*GI_SLOT;
            const unsigned* rz = (const unsigned*)slot;
            const u64* nn = (const u64*)(slot + 8192);
            pr0[s] = ld_u32_coh(rz + (tile0*2+0)*64 + lane);
            pz0[s] = ld_u32_coh(rz + (tile0*2+1)*64 + lane);
            pn0[s] = ld_u64_coh(nn + tile0*64 + lane);
            pr1[s] = ld_u32_coh(rz + (tile1*2+0)*64 + lane);
            pz1[s] = ld_u32_coh(rz + (tile1*2+1)*64 + lane);
            pn1[s] = ld_u64_coh(nn + tile1*64 + lane);
        }

#define A_STEP(T, P)                                                           \
        {                                                                      \
            if (((T) & 7) == 0) poll2_ge(&prog[P_M1], (T)+10, &prog[P_M2], (T)-24); \
            CFENCE();                                                          \
            f32x4 aR[2], aZ[2], aN[2]; float gn[2][2];                         \
            aR[0] = f32x4{bf2f_lo(pr0[P]), bf2f_hi(pr0[P]), 0.f, 0.f};         \
            aZ[0] = f32x4{bf2f_lo(pz0[P]), bf2f_hi(pz0[P]), 0.f, 0.f};         \
            aR[1] = f32x4{bf2f_lo(pr1[P]), bf2f_hi(pr1[P]), 0.f, 0.f};         \
            aZ[1] = f32x4{bf2f_lo(pz1[P]), bf2f_hi(pz1[P]), 0.f, 0.f};         \
            { union { u64 u; float f[2]; } c;                                  \
              c.u = pn0[P]; gn[0][0]=c.f[0]; gn[0][1]=c.f[1];                  \
              c.u = pn1[P]; gn[1][0]=c.f[0]; gn[1][1]=c.f[1]; }                \
            aN[0] = f32x4{bnn[0], bnn[0], 0.f, 0.f};                           \
            aN[1] = f32x4{bnn[1], bnn[1], 0.f, 0.f};                           \
            if ((T) + 2 < TT) {   /* prefetch gi1(T+2), 2-deep */              \
                char* slot = ws + OFF_GI1 + ((size_t)cl*RD1 + (((T)+2) & (RD1-1)))*GI_SLOT; \
                const unsigned* rz = (const unsigned*)slot;                    \
                const u64* nn = (const u64*)(slot + 8192);                     \
                pr0[P] = ld_u32_coh(rz + (tile0*2+0)*64 + lane);               \
                pz0[P] = ld_u32_coh(rz + (tile0*2+1)*64 + lane);               \
                pn0[P] = ld_u64_coh(nn + tile0*64 + lane);                     \
                pr1[P] = ld_u32_coh(rz + (tile1*2+0)*64 + lane);               \
                pz1[P] = ld_u32_coh(rz + (tile1*2+1)*64 + lane);               \
                pn1[P] = ld_u64_coh(nn + tile1*64 + lane);                     \
            }                                                                  \
            CFENCE();                                                          \
            const int rb = ((T) + 1) & 1, wb = (T) & 1;                        \
            _Pragma("unroll")                                                  \
            for (int kc = 0; kc < 8; ++kc) {                                   \
                bf16x8 f = *(const bf16x8*)&hb[rb][ln][kc*32 + qd*8];          \
                aR[0] = __builtin_amdgcn_mfma_f32_16x16x32_bf16(f, Wh[0][0][kc], aR[0], 0,0,0); \
                aR[1] = __builtin_amdgcn_mfma_f32_16x16x32_bf16(f, Wh[1][0][kc], aR[1], 0,0,0); \
                aZ[0] = __builtin_amdgcn_mfma_f32_16x16x32_bf16(f, Wh[0][1][kc], aZ[0], 0,0,0); \
                aZ[1] = __builtin_amdgcn_mfma_f32_16x16x32_bf16(f, Wh[1][1][kc], aZ[1], 0,0,0); \
                aN[0] = __builtin_amdgcn_mfma_f32_16x16x32_bf16(f, Wh[0][2][kc], aN[0], 0,0,0); \
                aN[1] = __builtin_amdgcn_mfma_f32_16x16x32_bf16(f, Wh[1][2][kc], aN[1], 0,0,0); \
            }                                                                  \
            CFENCE();                                                          \
            unsigned* h1slot = (unsigned*)(ws + OFF_H1R + ((size_t)cl*RD2 + ((T) & (RD2-1)))*4096u); \
            _Pragma("unroll")                                                  \
            for (int b2 = 0; b2 < 2; ++b2) {                                   \
                const int colg = (wave*2 + b2)*16 + ln;                        \
                unsigned pk = 0;                                               \
                _Pragma("unroll")                                              \
                for (int r = 0; r < 2; ++r) {                                  \
                    float rg = sigm_f(aR[b2][r]);                              \
                    float zg = sigm_f(aZ[b2][r]);                              \
                    float ng = tanh_f(gn[b2][r] + rg * aN[b2][r]);             \
                    float h  = (1.f - zg)*ng + zg*hold[b2][r];                 \
                    hold[b2][r] = h;                                           \
                    short hs = f2bf(h);                                        \
                    hb[wb][qd*4 + r][colg] = hs;                               \
                    pk |= (unsigned)(unsigned short)hs << (16*r);              \
                }                                                              \
                st_u32_coh(h1slot + colg*4 + qd, pk);                          \
            }                                                                  \
            if ((T) & 1) {                                                     \
                asm volatile("s_waitcnt vmcnt(8)" ::: "memory");               \
                if (tid == 0) post_prog(&prog[P_A], (T) - 1);                  \
            }                                                                  \
            asm volatile("s_waitcnt lgkmcnt(0)" ::: "memory");                 \
            __builtin_amdgcn_sched_barrier(0);                                 \
            __builtin_amdgcn_s_barrier();                                      \
        }
        for (int t = 0; t < TT; t += 2) {
            A_STEP(t,   0);
            A_STEP(t+1, 1);
        }
#undef A_STEP
        asm volatile("s_waitcnt vmcnt(0)" ::: "memory");
        __syncthreads();
        if (tid == 0) post_prog(&prog[P_A], 1000000);

    } else if (stage == 2) {
        // ================= M2: gi2 = h1 @ Wih2^T =================
        bf16x8 Wi[2][3][8]; float c0s[2][3];
        #pragma unroll
        for (int b2 = 0; b2 < 2; ++b2)
        #pragma unroll
        for (int g = 0; g < 3; ++g) {
            const int grow = g*256 + (wave*2 + b2)*16 + ln;
            #pragma unroll
            for (int kc = 0; kc < 8; ++kc)
                Wi[b2][g][kc] = ldfrag_f32(wih2 + grow*HH + kc*32 + qd*8);
            c0s[b2][g] = bih2[grow] + (g < 2 ? bhh2[grow] : 0.f);
        }
        const int base = (tid & 1) * 8, pcol = tid >> 1;
        u64 vc[2];

        // prologue: h1(0) -> hb[0]; vc[0] <- h1(1) (use u=0); vc[1] <- h1(2) (use u=1)
        poll_ge(&prog[P_A], 2);
        {
            const u64* h1s = (const u64*)(ws + OFF_H1R + (size_t)cl*RD2*4096u);
            u64 v = ld_u64_coh(h1s + tid);
            unsigned lo = (unsigned)v, hi = (unsigned)(v >> 32);
            hb[0][base + 0][pcol] = (short)lo;
            hb[0][base + 1][pcol] = (short)(lo >> 16);
            hb[0][base + 4][pcol] = (short)hi;
            hb[0][base + 5][pcol] = (short)(hi >> 16);
        }
        vc[0] = ld_u64_coh((const u64*)(ws + OFF_H1R + ((size_t)cl*RD2 + 1)*4096u) + tid);
        vc[1] = ld_u64_coh((const u64*)(ws + OFF_H1R + ((size_t)cl*RD2 + 2)*4096u) + tid);
        __syncthreads();

#define M2_STEP(U, P)                                                          \
        {                                                                      \
            if (((U) & 7) == 0) poll2_ge(&prog[P_A], (U)+11, &prog[P_B], (U)-24); \
            CFENCE();                                                          \
            if ((U) + 1 < TT) {   /* unpack h1(U+1), loaded 2 iters ago */     \
                unsigned lo = (unsigned)vc[P], hi = (unsigned)(vc[P] >> 32);   \
                hb[((U)+1) & 1][base + 0][pcol] = (short)lo;                   \
                hb[((U)+1) & 1][base + 1][pcol] = (short)(lo >> 16);           \
                hb[((U)+1) & 1][base + 4][pcol] = (short)hi;                   \
                hb[((U)+1) & 1][base + 5][pcol] = (short)(hi >> 16);           \
            }                                                                  \
            if ((U) + 3 < TT)                                                  \
                vc[P] = ld_u64_coh((const u64*)(ws + OFF_H1R + ((size_t)cl*RD2 + (((U)+3) & (RD2-1)))*4096u) + tid); \
            CFENCE();                                                          \
            f32x4 acc[2][3];                                                   \
            _Pragma("unroll")                                                  \
            for (int b2 = 0; b2 < 2; ++b2)                                     \
            _Pragma("unroll")                                                  \
            for (int g = 0; g < 3; ++g) {                                      \
                float c0 = c0s[b2][g];                                         \
                acc[b2][g] = f32x4{c0, c0, c0, c0};                            \
            }                                                                  \
            _Pragma("unroll")                                                  \
            for (int kc = 0; kc < 8; ++kc) {                                   \
                bf16x8 f = *(const bf16x8*)&hb[(U) & 1][ln][kc*32 + qd*8];     \
                _Pragma("unroll")                                              \
                for (int b2 = 0; b2 < 2; ++b2)                                 \
                _Pragma("unroll")                                              \
                for (int g = 0; g < 3; ++g)                                    \
                    acc[b2][g] = __builtin_amdgcn_mfma_f32_16x16x32_bf16(f, Wi[b2][g][kc], acc[b2][g], 0, 0, 0); \
            }                                                                  \
            CFENCE();                                                          \
            char* slot = ws + OFF_GI2 + ((size_t)cl*RD2 + ((U) & (RD2-1)))*GI_SLOT; \
            unsigned* rz = (unsigned*)slot;                                    \
            u64* nn = (u64*)(slot + 8192);                                     \
            _Pragma("unroll")                                                  \
            for (int b2 = 0; b2 < 2; ++b2) {                                   \
                const int tile = wave*2 + b2;                                  \
                st_u32_coh(rz + (tile*2 + 0)*64 + lane, pk2bf(acc[b2][0][0], acc[b2][0][1])); \
                st_u32_coh(rz + (tile*2 + 1)*64 + lane, pk2bf(acc[b2][1][0], acc[b2][1][1])); \
                union { float f[2]; u64 u; } np;                               \
                np.f[0] = acc[b2][2][0]; np.f[1] = acc[b2][2][1];              \
                st_u64_coh(nn + tile*64 + lane, np.u);                         \
            }                                                                  \
            if ((U) & 1) {                                                     \
                asm volatile("s_waitcnt vmcnt(7)" ::: "memory");               \
                if (tid == 0) post_prog(&prog[P_M2], (U) - 1);                 \
            }                                                                  \
            asm volatile("s_waitcnt lgkmcnt(0)" ::: "memory");                 \
            __builtin_amdgcn_sched_barrier(0);                                 \
            __builtin_amdgcn_s_barrier();                                      \
        }
        for (int u = 0; u < TT; u += 2) {
            M2_STEP(u,   0);
            M2_STEP(u+1, 1);
        }
#undef M2_STEP
        asm volatile("s_waitcnt vmcnt(0)" ::: "memory");
        __syncthreads();
        if (tid == 0) post_prog(&prog[P_M2], 1000000);

    } else {
        // ================= B: layer-2 recurrence + h2seq + BN =================
        bf16x8 Wh[2][3][8]; float bnn[2];
        #pragma unroll
        for (int b2 = 0; b2 < 2; ++b2) {
            const int colg = (wave*2 + b2)*16 + ln;
            #pragma unroll
            for (int g = 0; g < 3; ++g)
                #pragma unroll
                for (int kc = 0; kc < 8; ++kc)
                    Wh[b2][g][kc] = ldfrag_f32(whh2 + (g*256 + colg)*HH + kc*32 + qd*8);
            bnn[b2] = bhh2[512 + colg];
        }
        float* bnsum = (float*)(ws + OFF_BNSUM);
        float* bnsq  = (float*)(ws + OFF_BNSQ);
        float hold[2][2] = {{0.f,0.f},{0.f,0.f}};
        float cbs[2] = {0.f, 0.f}, cbq[2] = {0.f, 0.f};
        unsigned pr0[2], pz0[2], pr1[2], pz1[2]; u64 pn0[2], pn1[2];
        const int tile0 = wave*2, tile1 = wave*2 + 1;

        // prologue: gi2(0) -> set0, gi2(1) -> set1
        poll_ge(&prog[P_M2], 2);
        #pragma unroll
        for (int s = 0; s < 2; ++s) {
            char* slot = ws + OFF_GI2 + ((size_t)cl*RD2 + s)*GI_SLOT;
            const unsigned* rz = (const unsigned*)slot;
            const u64* nn = (const u64*)(slot + 8192);
            pr0[s] = ld_u32_coh(rz + (tile0*2+0)*64 + lane);
            pz0[s] = ld_u32_coh(rz + (tile0*2+1)*64 + lane);
            pn0[s] = ld_u64_coh(nn + tile0*64 + lane);
            pr1[s] = ld_u32_coh(rz + (tile1*2+0)*64 + lane);
            pz1[s] = ld_u32_coh(rz + (tile1*2+1)*64 + lane);
            pn1[s] = ld_u64_coh(nn + tile1*64 + lane);
        }
        __syncthreads();

#define B_STEP(V, P)                                                           \
        {                                                                      \
            if (((V) & 7) == 0) poll_ge(&prog[P_M2], (V)+10);                  \
            CFENCE();                                                          \
            f32x4 aR[2], aZ[2], aN[2]; float gn[2][2];                         \
            aR[0] = f32x4{bf2f_lo(pr0[P]), bf2f_hi(pr0[P]), 0.f, 0.f};         \
            aZ[0] = f32x4{bf2f_lo(pz0[P]), bf2f_hi(pz0[P]), 0.f, 0.f};         \
            aR[1] = f32x4{bf2f_lo(pr1[P]), bf2f_hi(pr1[P]), 0.f, 0.f};         \
            aZ[1] = f32x4{bf2f_lo(pz1[P]), bf2f_hi(pz1[P]), 0.f, 0.f};         \
            { union { u64 u; float f[2]; } c;                                  \
              c.u = pn0[P]; gn[0][0]=c.f[0]; gn[0][1]=c.f[1];                  \
              c.u = pn1[P]; gn[1][0]=c.f[0]; gn[1][1]=c.f[1]; }                \
            aN[0] = f32x4{bnn[0], bnn[0], 0.f, 0.f};                           \
            aN[1] = f32x4{bnn[1], bnn[1], 0.f, 0.f};                           \
            if ((V) + 2 < TT) {   /* prefetch gi2(V+2), 2-deep */              \
                char* slot = ws + OFF_GI2 + ((size_t)cl*RD2 + (((V)+2) & (RD2-1)))*GI_SLOT; \
                const unsigned* rz = (const unsigned*)slot;                    \
                const u64* nn = (const u64*)(slot + 8192);                     \
                pr0[P] = ld_u32_coh(rz + (tile0*2+0)*64 + lane);               \
                pz0[P] = ld_u32_coh(rz + (tile0*2+1)*64 + lane);               \
                pn0[P] = ld_u64_coh(nn + tile0*64 + lane);                     \
                pr1[P] = ld_u32_coh(rz + (tile1*2+0)*64 + lane);               \
                pz1[P] = ld_u32_coh(rz + (tile1*2+1)*64 + lane);               \
                pn1[P] = ld_u64_coh(nn + tile1*64 + lane);                     \
            }                                                                  \
            CFENCE();                                                          \
            const int rb = ((V) + 1) & 1, wb = (V) & 1;                        \
            _Pragma("unroll")                                                  \
            for (int kc = 0; kc < 8; ++kc) {                                   \
                bf16x8 f = *(const bf16x8*)&hb[rb][ln][kc*32 + qd*8];          \
                aR[0] = __builtin_amdgcn_mfma_f32_16x16x32_bf16(f, Wh[0][0][kc], aR[0], 0,0,0); \
                aR[1] = __builtin_amdgcn_mfma_f32_16x16x32_bf16(f, Wh[1][0][kc], aR[1], 0,0,0); \
                aZ[0] = __builtin_amdgcn_mfma_f32_16x16x32_bf16(f, Wh[0][1][kc], aZ[0], 0,0,0); \
                aZ[1] = __builtin_amdgcn_mfma_f32_16x16x32_bf16(f, Wh[1][1][kc], aZ[1], 0,0,0); \
                aN[0] = __builtin_amdgcn_mfma_f32_16x16x32_bf16(f, Wh[0][2][kc], aN[0], 0,0,0); \
                aN[1] = __builtin_amdgcn_mfma_f32_16x16x32_bf16(f, Wh[1][2][kc], aN[1], 0,0,0); \
            }                                                                  \
            CFENCE();                                                          \
            _Pragma("unroll")                                                  \
            for (int b2 = 0; b2 < 2; ++b2) {                                   \
                const int colg = (wave*2 + b2)*16 + ln;                        \
                _Pragma("unroll")                                              \
                for (int r = 0; r < 2; ++r) {                                  \
                    float rg = sigm_f(aR[b2][r]);                              \
                    float zg = sigm_f(aZ[b2][r]);                              \
                    float ng = tanh_f(gn[b2][r] + rg * aN[b2][r]);             \
                    float h  = (1.f - zg)*ng + zg*hold[b2][r];                 \
                    hold[b2][r] = h;                                           \
                    cbs[b2] += h; cbq[b2] += h*h;                              \
                    short hs = f2bf(h);                                        \
                    hb[wb][qd*4 + r][colg] = hs;                               \
                    h2seq[((size_t)(V)*BB + grow0 + qd*2 + r)*HH + colg] = hs; \
                }                                                              \
            }                                                                  \
            if (((V) & 1) && tid == 0) post_prog(&prog[P_B], (V) - 1);         \
            asm volatile("s_waitcnt lgkmcnt(0)" ::: "memory");                 \
            __builtin_amdgcn_sched_barrier(0);                                 \
            __builtin_amdgcn_s_barrier();                                      \
        }
        for (int v = 0; v < TT; v += 2) {
            B_STEP(v,   0);
            B_STEP(v+1, 1);
        }
#undef B_STEP
        #pragma unroll
        for (int b2 = 0; b2 < 2; ++b2) {
            const int colg = (wave*2 + b2)*16 + ln;
            atomicAdd(&bnsum[colg], cbs[b2]);
            atomicAdd(&bnsq[colg],  cbq[b2]);
        }
        __syncthreads();
        if (tid == 0) post_prog(&prog[P_B], 1000000);
    }
}

// ---------------- BN finalize + hardtanh + temporal mean + FC ----------------
__global__ void gru_final(const char* __restrict__ ws,
                          const float* __restrict__ gamma, const float* __restrict__ beta,
                          const float* __restrict__ fcw, const float* __restrict__ fcb,
                          float* __restrict__ out)
{
    __shared__ float summ[HH];
    const int b = blockIdx.x, c = threadIdx.x;
    const float* bnsum = (const float*)(ws + OFF_BNSUM);
    const float* bnsq  = (const float*)(ws + OFF_BNSQ);
    const short* h2seq = (const short*)(ws + OFF_H2SEQ);

    const float inv = 1.f / (float)(BB * TT);
    float mean = bnsum[c] * inv;
    float var  = bnsq[c] * inv - mean * mean;
    float scale = rsqrtf(var + EPSV) * gamma[c];
    float shift = beta[c] - mean * scale;

    const short* p = h2seq + (size_t)b*HH + c;    // [t][b][h]
    float acc = 0.f;
    #pragma unroll 4
    for (int t = 0; t < TT; ++t) {
        float v = bf2f(p[(size_t)t*BB*HH]) * scale + shift;
        v = fminf(fmaxf(v, -2.f), 2.f);
        acc += v;
    }
    summ[c] = acc * (1.f / TT);
    __syncthreads();
    if (c < OUTD) {
        float d = fcb[c];
        const float* wr = fcw + c*HH;
        #pragma unroll 8
        for (int h = 0; h < HH; ++h) d += wr[h] * summ[h];
        out[b*OUTD + c] = d;
    }
}

extern "C" void kernel_launch(void* const* d_in, const int* in_sizes, int n_in,
                              void* d_out, int out_size, void* d_ws, size_t ws_size,
                              hipStream_t stream)
{
    const float* x    = (const float*)d_in[0];
    const float* wih1 = (const float*)d_in[1];
    const float* whh1 = (const float*)d_in[2];
    const float* bih1 = (const float*)d_in[3];
    const float* bhh1 = (const float*)d_in[4];
    const float* wih2 = (const float*)d_in[5];
    const float* whh2 = (const float*)d_in[6];
    const float* bih2 = (const float*)d_in[7];
    const float* bhh2 = (const float*)d_in[8];
    const float* gamma= (const float*)d_in[9];
    const float* beta = (const float*)d_in[10];
    const float* fcw  = (const float*)d_in[11];
    const float* fcb  = (const float*)d_in[12];
    char* ws = (char*)d_ws;

    // progress counters + BN accumulators start at 0 (re-zeroed every replay)
    (void)hipMemsetAsync(ws, 0, OFF_ZERO_END, stream);

    // 32 clusters x 4 stages = 128 co-resident WGs (one per CU)
    hipLaunchKernelGGL(gru_pipe, dim3(NCL*4), dim3(512), 0, stream,
                       x, wih1, whh1, bih1, bhh1, wih2, whh2, bih2, bhh2, ws);

    hipLaunchKernelGGL(gru_final, dim3(BB), dim3(HH), 0, stream,
                       (const char*)ws, gamma, beta, fcw, fcb, (float*)d_out);
}